// Round 4
// baseline (1162.145 us; speedup 1.0000x reference)
//
#include <hip/hip_runtime.h>
#include <hip/hip_bf16.h>
#include <stdint.h>

#define TOKS 16384
#define HDIM 2048
#define IDIM 1024
#define NEXP 8
#define TOPK 2
#define NPAIR (TOKS*TOPK)   // 32768

typedef __attribute__((ext_vector_type(4))) float f32x4;
typedef __attribute__((ext_vector_type(8))) __bf16 bf16x8;
typedef __attribute__((ext_vector_type(8))) unsigned short u16x8;

// async global->LDS, 16B per lane; LDS dest is wave-uniform base, HW adds lane*16
#define GLOAD_LDS16(gp, lp) \
  __builtin_amdgcn_global_load_lds((const __attribute__((address_space(1))) void*)(gp), \
                                   (__attribute__((address_space(3))) void*)(lp), 16, 0, 0)

__device__ __forceinline__ unsigned short f2bf(float f) {
  unsigned int u = __float_as_uint(f);
  u += 0x7FFF + ((u >> 16) & 1);   // RNE
  return (unsigned short)(u >> 16);
}

// ---------------- conversion: f32 -> bf16, 8 elems/thread ----------------
__global__ __launch_bounds__(256) void cvt_bf16(const float* __restrict__ src,
                                                unsigned short* __restrict__ dst,
                                                int n8) {
  int i = blockIdx.x * 256 + threadIdx.x;
  if (i >= n8) return;
  const float4* s = (const float4*)src + (size_t)i * 2;
  float4 a = s[0], b = s[1];
  u16x8 o;
  o[0] = f2bf(a.x); o[1] = f2bf(a.y); o[2] = f2bf(a.z); o[3] = f2bf(a.w);
  o[4] = f2bf(b.x); o[5] = f2bf(b.y); o[6] = f2bf(b.z); o[7] = f2bf(b.w);
  *((u16x8*)dst + i) = o;
}

// ---------------- routing ----------------
// ctrl layout (ints): [0..7]=counts, [8..15]=offsets, [16..23]=cursors
__global__ void route_count(const int* __restrict__ ert, int* __restrict__ ctrl) {
  int p = blockIdx.x * 256 + threadIdx.x;
  if (p < NPAIR) atomicAdd(&ctrl[ert[p]], 1);
}

__global__ void route_scan(int* __restrict__ ctrl) {
  if (blockIdx.x == 0 && threadIdx.x == 0) {
    int off = 0;
    for (int e = 0; e < NEXP; ++e) { ctrl[8 + e] = off; ctrl[16 + e] = off; off += ctrl[e]; }
  }
}

__global__ void route_scatter(const int* __restrict__ ert, const float* __restrict__ rw,
                              int* __restrict__ ctrl, int* __restrict__ ptok,
                              float* __restrict__ pcoef) {
  int p = blockIdx.x * 256 + threadIdx.x;
  if (p < NPAIR) {
    int e = ert[p];
    int pos = atomicAdd(&ctrl[16 + e], 1);
    ptok[pos] = p >> 1;          // TOPK = 2
    pcoef[pos] = rw[p];
  }
}

// ============ GEMM1: act = silu(x@Wg^T)*(x@Wu^T), 256x256 deep-pipelined ============
// block: 512 thr (8 waves 2Mx4N). Tile 256 pair-rows x 256 B-rows (=128 act cols,
// gate+up fused via B-row remap). K pair-step = 64, buf[2] x (A 32KB + B 32KB).
__global__ __launch_bounds__(512, 2) void gemm1(const unsigned short* __restrict__ xb,
                                                const unsigned short* __restrict__ w13b,
                                                const int* __restrict__ ctrl,
                                                const int* __restrict__ ptok,
                                                unsigned short* __restrict__ actb) {
  __shared__ __align__(16) char lds[131072];
  const int bid = blockIdx.x;
  const int e   = bid & 7;             // XCD-aware: each XCD owns one expert
  const int rb0 = (bid >> 3) & 15;
  const int cb  = bid >> 7;            // 0..7
  const int c0  = cb * 128;            // act col base
  const int Ne   = ctrl[e];
  const int base = ctrl[8 + e];
  const int tid  = threadIdx.x;
  const int wid  = tid >> 6;
  const int lane = tid & 63;
  const int wr   = wid >> 2;           // 0..1 (M)
  const int wc   = wid & 3;            // 0..3 (N)
  const int l15  = lane & 15;
  const int l16  = lane >> 4;
  const int NP   = HDIM / 64;          // 32 pair-steps

  // B staging pointers (rb-independent), source pre-swizzled
  const unsigned short* gB[4];
  #pragma unroll
  for (int j = 0; j < 4; ++j) {
    int nb = j * 64 + wid * 8 + (lane >> 3);       // B-tile row 0..255
    int c8 = (lane & 7) ^ (nb & 7);
    // gate/up interleave: nb&32 selects up half (w13 row IDIM+col);
    // act col = c0 + (nb>>6)*32 + (nb&31).  (fixed: was IDIM-32, off by -32)
    int grow = ((nb & 32) ? IDIM : 0) + c0 + ((nb >> 6) << 5) + (nb & 31);
    gB[j] = w13b + ((size_t)e * (2 * IDIM) + grow) * HDIM + c8 * 8;
  }

  for (int rb = rb0; rb * 256 < Ne; rb += 16) {
    const int row0 = rb * 256;
    __syncthreads();                    // full drain (incl. prev-rb stores)

    const unsigned short* gA[4];
    #pragma unroll
    for (int j = 0; j < 4; ++j) {
      int r = j * 64 + wid * 8 + (lane >> 3);
      int c8 = (lane & 7) ^ (r & 7);
      int rr = row0 + r; if (rr > Ne - 1) rr = Ne - 1;
      gA[j] = xb + (size_t)ptok[base + rr] * HDIM + c8 * 8;
    }

    f32x4 acc[2][2][4][2];
    #pragma unroll
    for (int qm = 0; qm < 2; ++qm)
      #pragma unroll
      for (int qn = 0; qn < 2; ++qn)
        #pragma unroll
        for (int mi = 0; mi < 4; ++mi)
          #pragma unroll
          for (int ni = 0; ni < 2; ++ni) acc[qm][qn][mi][ni] = (f32x4)(0.0f);

    auto STAGE = [&](int kt) {
      char* d = lds + (kt & 1) * 65536 + wid * 1024;
      #pragma unroll
      for (int j = 0; j < 4; ++j) GLOAD_LDS16(gA[j] + kt * 64, d + j * 8192);
      #pragma unroll
      for (int j = 0; j < 4; ++j) GLOAD_LDS16(gB[j] + kt * 64, d + 32768 + j * 8192);
    };

    STAGE(0); STAGE(1);

    for (int i = 0; i < NP; ++i) {
      if (i >= 1 && i + 1 < NP) STAGE(i + 1);
      if (i < NP - 1) asm volatile("s_waitcnt vmcnt(8)" ::: "memory");
      else            asm volatile("s_waitcnt vmcnt(0)" ::: "memory");
      __builtin_amdgcn_s_barrier();
      __builtin_amdgcn_sched_barrier(0);

      const char* lb = lds + (i & 1) * 65536;
      bf16x8 af[2][4], bf[2][2];
      #pragma unroll
      for (int p = 0; p < 4; ++p) {
        const int qm = p >> 1, qn = p & 1;
        if (qn == 0) {
          #pragma unroll
          for (int ks = 0; ks < 2; ++ks)
            #pragma unroll
            for (int mi = 0; mi < 4; ++mi) {
              int r = wr * 128 + qm * 64 + mi * 16 + l15;
              int j = ks * 4 + l16;
              af[ks][mi] = *(const bf16x8*)(lb + r * 128 + ((j ^ (r & 7)) << 4));
            }
        }
        #pragma unroll
        for (int ks = 0; ks < 2; ++ks)
          #pragma unroll
          for (int ni = 0; ni < 2; ++ni) {
            int nb = wc * 64 + qn * 32 + ni * 16 + l15;
            int j = ks * 4 + l16;
            bf[ks][ni] = *(const bf16x8*)(lb + 32768 + nb * 128 + ((j ^ (nb & 7)) << 4));
          }
        __builtin_amdgcn_s_barrier();
        asm volatile("s_waitcnt lgkmcnt(0)" ::: "memory");
        __builtin_amdgcn_sched_barrier(0);
        __builtin_amdgcn_s_setprio(1);
        #pragma unroll
        for (int ks = 0; ks < 2; ++ks)
          #pragma unroll
          for (int mi = 0; mi < 4; ++mi)
            #pragma unroll
            for (int ni = 0; ni < 2; ++ni)
              acc[qm][qn][mi][ni] = __builtin_amdgcn_mfma_f32_16x16x32_bf16(
                  af[ks][mi], bf[ks][ni], acc[qm][qn][mi][ni], 0, 0, 0);
        __builtin_amdgcn_s_setprio(0);
        __builtin_amdgcn_s_barrier();
      }
    }

    // epilogue: silu(gate)*up -> bf16 act (qn=0 frags are gate, qn=1 are up)
    #pragma unroll
    for (int qm = 0; qm < 2; ++qm)
      #pragma unroll
      for (int mi = 0; mi < 4; ++mi)
        #pragma unroll
        for (int jj = 0; jj < 4; ++jj) {
          int r = wr * 128 + qm * 64 + mi * 16 + l16 * 4 + jj;
          int rr = row0 + r;
          if (rr < Ne) {
            #pragma unroll
            for (int ni = 0; ni < 2; ++ni) {
              float g = acc[qm][0][mi][ni][jj];
              float u = acc[qm][1][mi][ni][jj];
              float a = g / (1.0f + __expf(-g)) * u;
              actb[(size_t)(base + rr) * IDIM + (c0 + wc * 32 + ni * 16 + l15)] = f2bf(a);
            }
          }
        }
  }
}

// ============ GEMM2: out += coef * (act @ w2^T), 256x256 deep-pipelined ============
__global__ __launch_bounds__(512, 2) void gemm2(const unsigned short* __restrict__ actb,
                                                const unsigned short* __restrict__ w2b,
                                                const int* __restrict__ ctrl,
                                                const int* __restrict__ ptok,
                                                const float* __restrict__ pcoef,
                                                float* __restrict__ out) {
  __shared__ __align__(16) char lds[133120];   // 128KB tiles + ltok/lcoef
  int*   ltok  = (int*)(lds + 131072);
  float* lcoef = (float*)(lds + 131072 + 1024);
  const int bid = blockIdx.x;
  const int e   = bid & 7;
  const int rb0 = (bid >> 3) & 15;
  const int cb  = bid >> 7;
  const int n0  = cb * 256;            // out col base
  const int Ne   = ctrl[e];
  const int base = ctrl[8 + e];
  const int tid  = threadIdx.x;
  const int wid  = tid >> 6;
  const int lane = tid & 63;
  const int wr   = wid >> 2;
  const int wc   = wid & 3;
  const int l15  = lane & 15;
  const int l16  = lane >> 4;
  const int NP   = IDIM / 64;          // 16 pair-steps

  const unsigned short* gB[4];
  #pragma unroll
  for (int j = 0; j < 4; ++j) {
    int nb = j * 64 + wid * 8 + (lane >> 3);
    int c8 = (lane & 7) ^ (nb & 7);
    gB[j] = w2b + ((size_t)e * HDIM + n0 + nb) * IDIM + c8 * 8;
  }

  for (int rb = rb0; rb * 256 < Ne; rb += 16) {
    const int row0 = rb * 256;
    __syncthreads();                    // full drain (incl. prev-rb atomics)

    if (tid < 256) {
      int rr = row0 + tid;
      bool v = rr < Ne;
      ltok[tid]  = v ? ptok[base + rr]  : 0;
      lcoef[tid] = v ? pcoef[base + rr] : 0.0f;
    }

    const unsigned short* gA[4];
    #pragma unroll
    for (int j = 0; j < 4; ++j) {
      int r = j * 64 + wid * 8 + (lane >> 3);
      int c8 = (lane & 7) ^ (r & 7);
      int rr = row0 + r; if (rr > Ne - 1) rr = Ne - 1;
      gA[j] = actb + (size_t)(base + rr) * IDIM + c8 * 8;
    }

    f32x4 acc[2][2][4][2];
    #pragma unroll
    for (int qm = 0; qm < 2; ++qm)
      #pragma unroll
      for (int qn = 0; qn < 2; ++qn)
        #pragma unroll
        for (int mi = 0; mi < 4; ++mi)
          #pragma unroll
          for (int ni = 0; ni < 2; ++ni) acc[qm][qn][mi][ni] = (f32x4)(0.0f);

    auto STAGE = [&](int kt) {
      char* d = lds + (kt & 1) * 65536 + wid * 1024;
      #pragma unroll
      for (int j = 0; j < 4; ++j) GLOAD_LDS16(gA[j] + kt * 64, d + j * 8192);
      #pragma unroll
      for (int j = 0; j < 4; ++j) GLOAD_LDS16(gB[j] + kt * 64, d + 32768 + j * 8192);
    };

    STAGE(0); STAGE(1);

    for (int i = 0; i < NP; ++i) {
      if (i >= 1 && i + 1 < NP) STAGE(i + 1);
      if (i < NP - 1) asm volatile("s_waitcnt vmcnt(8)" ::: "memory");
      else            asm volatile("s_waitcnt vmcnt(0)" ::: "memory");
      __builtin_amdgcn_s_barrier();
      __builtin_amdgcn_sched_barrier(0);

      const char* lb = lds + (i & 1) * 65536;
      bf16x8 af[2][4], bf[2][2];
      #pragma unroll
      for (int p = 0; p < 4; ++p) {
        const int qm = p >> 1, qn = p & 1;
        if (qn == 0) {
          #pragma unroll
          for (int ks = 0; ks < 2; ++ks)
            #pragma unroll
            for (int mi = 0; mi < 4; ++mi) {
              int r = wr * 128 + qm * 64 + mi * 16 + l15;
              int j = ks * 4 + l16;
              af[ks][mi] = *(const bf16x8*)(lb + r * 128 + ((j ^ (r & 7)) << 4));
            }
        }
        #pragma unroll
        for (int ks = 0; ks < 2; ++ks)
          #pragma unroll
          for (int ni = 0; ni < 2; ++ni) {
            int nb = wc * 64 + qn * 32 + ni * 16 + l15;
            int j = ks * 4 + l16;
            bf[ks][ni] = *(const bf16x8*)(lb + 32768 + nb * 128 + ((j ^ (nb & 7)) << 4));
          }
        __builtin_amdgcn_s_barrier();
        asm volatile("s_waitcnt lgkmcnt(0)" ::: "memory");
        __builtin_amdgcn_sched_barrier(0);
        __builtin_amdgcn_s_setprio(1);
        #pragma unroll
        for (int ks = 0; ks < 2; ++ks)
          #pragma unroll
          for (int mi = 0; mi < 4; ++mi)
            #pragma unroll
            for (int ni = 0; ni < 2; ++ni)
              acc[qm][qn][mi][ni] = __builtin_amdgcn_mfma_f32_16x16x32_bf16(
                  af[ks][mi], bf[ks][ni], acc[qm][qn][mi][ni], 0, 0, 0);
        __builtin_amdgcn_s_setprio(0);
        __builtin_amdgcn_s_barrier();
      }
    }

    // epilogue: atomic scatter with router coef
    #pragma unroll
    for (int qm = 0; qm < 2; ++qm)
      #pragma unroll
      for (int mi = 0; mi < 4; ++mi)
        #pragma unroll
        for (int jj = 0; jj < 4; ++jj) {
          int r = wr * 128 + qm * 64 + mi * 16 + l16 * 4 + jj;
          if (row0 + r < Ne) {
            int   t  = ltok[r];
            float cf = lcoef[r];
            #pragma unroll
            for (int qn = 0; qn < 2; ++qn)
              #pragma unroll
              for (int ni = 0; ni < 2; ++ni) {
                int col = n0 + wc * 64 + qn * 32 + ni * 16 + l15;
                atomicAdd(&out[(size_t)t * HDIM + col], acc[qm][qn][mi][ni][jj] * cf);
              }
          }
        }
  }
}

// ---------------- launcher ----------------
extern "C" void kernel_launch(void* const* d_in, const int* in_sizes, int n_in,
                              void* d_out, int out_size, void* d_ws, size_t ws_size,
                              hipStream_t stream) {
  const float* x   = (const float*)d_in[0];
  const int*   ert = (const int*)d_in[1];
  const float* rw  = (const float*)d_in[2];
  const float* w13 = (const float*)d_in[3];
  const float* w2  = (const float*)d_in[4];
  float* out = (float*)d_out;

  char* ws = (char*)d_ws;
  size_t off = 0;
  auto alloc = [&](size_t bytes) { char* p = ws + off; off += (bytes + 255) & ~255ULL; return p; };
  int*            ctrl  = (int*)           alloc(256);
  int*            ptok  = (int*)           alloc((size_t)NPAIR * 4);
  float*          pcoef = (float*)         alloc((size_t)NPAIR * 4);
  unsigned short* w13b  = (unsigned short*)alloc((size_t)NEXP * 2 * IDIM * HDIM * 2);
  unsigned short* w2b   = (unsigned short*)alloc((size_t)NEXP * HDIM * IDIM * 2);
  unsigned short* xb    = (unsigned short*)alloc((size_t)TOKS * HDIM * 2);
  unsigned short* actb  = (unsigned short*)alloc((size_t)NPAIR * IDIM * 2);

  hipMemsetAsync(ctrl, 0, 256, stream);
  hipMemsetAsync(out, 0, (size_t)out_size * 4, stream);

  cvt_bf16<<<(NEXP * 2 * IDIM * HDIM / 8) / 256, 256, 0, stream>>>(w13, w13b, NEXP * 2 * IDIM * HDIM / 8);
  cvt_bf16<<<(NEXP * HDIM * IDIM / 8) / 256, 256, 0, stream>>>(w2, w2b, NEXP * HDIM * IDIM / 8);
  cvt_bf16<<<(TOKS * HDIM / 8) / 256, 256, 0, stream>>>(x, xb, TOKS * HDIM / 8);

  route_count  <<<NPAIR / 256, 256, 0, stream>>>(ert, ctrl);
  route_scan   <<<1, 64, 0, stream>>>(ctrl);
  route_scatter<<<NPAIR / 256, 256, 0, stream>>>(ert, rw, ctrl, ptok, pcoef);

  gemm1<<<1024, 512, 0, stream>>>(xb, w13b, ctrl, ptok, actb);
  gemm2<<<1024, 512, 0, stream>>>(actb, w2b, ctrl, ptok, pcoef, out);
}

// Round 5
// 1084.756 us; speedup vs baseline: 1.0713x; 1.0713x over previous
//
#include <hip/hip_runtime.h>
#include <hip/hip_bf16.h>
#include <stdint.h>

#define TOKS 16384
#define HDIM 2048
#define IDIM 1024
#define NEXP 8
#define TOPK 2
#define NPAIR (TOKS*TOPK)   // 32768

typedef __attribute__((ext_vector_type(4))) float f32x4;
typedef __attribute__((ext_vector_type(8))) __bf16 bf16x8;
typedef __attribute__((ext_vector_type(8))) unsigned short u16x8;

#define GLOAD_LDS16(gp, lp) \
  __builtin_amdgcn_global_load_lds((const __attribute__((address_space(1))) void*)(gp), \
                                   (__attribute__((address_space(3))) void*)(lp), 16, 0, 0)

#define LGKM_WAIT(n) do { asm volatile("s_waitcnt lgkmcnt(" #n ")" ::: "memory"); \
                          __builtin_amdgcn_sched_barrier(0); } while (0)
#define VM_WAIT0()   asm volatile("s_waitcnt vmcnt(0)" ::: "memory")

__device__ __forceinline__ unsigned short f2bf(float f) {
  unsigned int u = __float_as_uint(f);
  u += 0x7FFF + ((u >> 16) & 1);   // RNE
  return (unsigned short)(u >> 16);
}
__device__ __forceinline__ float bf2f(unsigned short h) {
  return __uint_as_float(((unsigned int)h) << 16);
}

// ---------------- conversion: f32 -> bf16, 8 elems/thread ----------------
__global__ __launch_bounds__(256) void cvt_bf16(const float* __restrict__ src,
                                                unsigned short* __restrict__ dst,
                                                int n8) {
  int i = blockIdx.x * 256 + threadIdx.x;
  if (i >= n8) return;
  const float4* s = (const float4*)src + (size_t)i * 2;
  float4 a = s[0], b = s[1];
  u16x8 o;
  o[0] = f2bf(a.x); o[1] = f2bf(a.y); o[2] = f2bf(a.z); o[3] = f2bf(a.w);
  o[4] = f2bf(b.x); o[5] = f2bf(b.y); o[6] = f2bf(b.z); o[7] = f2bf(b.w);
  *((u16x8*)dst + i) = o;
}

// ---------------- routing ----------------
__global__ void route_count(const int* __restrict__ ert, int* __restrict__ ctrl) {
  int p = blockIdx.x * 256 + threadIdx.x;
  if (p < NPAIR) atomicAdd(&ctrl[ert[p]], 1);
}

__global__ void route_scan(int* __restrict__ ctrl) {
  if (blockIdx.x == 0 && threadIdx.x == 0) {
    int off = 0;
    for (int e = 0; e < NEXP; ++e) { ctrl[8 + e] = off; ctrl[16 + e] = off; off += ctrl[e]; }
  }
}

__global__ void route_scatter(const int* __restrict__ ert, const float* __restrict__ rw,
                              int* __restrict__ ctrl, int* __restrict__ porig,
                              float* __restrict__ pcoef) {
  int p = blockIdx.x * 256 + threadIdx.x;
  if (p < NPAIR) {
    int e = ert[p];
    int pos = atomicAdd(&ctrl[16 + e], 1);
    porig[pos] = p;              // original pair slot (token = p>>1)
    pcoef[pos] = rw[p];
  }
}

// ============ GEMM1: act = silu(x@Wg^T)*(x@Wu^T) ============
// 512 thr (8 waves 2Mx4N), tile 256 pair-rows x 256 B-rows (=128 act cols).
// BK=64, double-buffered LDS, software-pipelined register prefetch:
// counted lgkmcnt, one s_barrier per K-iter, waves drift for MFMA||LDS overlap.
__global__ __launch_bounds__(512, 2) void gemm1(const unsigned short* __restrict__ xb,
                                                const unsigned short* __restrict__ w13b,
                                                const int* __restrict__ ctrl,
                                                const int* __restrict__ porig,
                                                unsigned short* __restrict__ actb) {
  __shared__ __align__(16) char lds[131072];
  const int bid = blockIdx.x;
  const int e   = bid & 7;
  const int rb0 = (bid >> 3) & 15;
  const int cb  = bid >> 7;
  const int c0  = cb * 128;
  const int Ne   = ctrl[e];
  const int base = ctrl[8 + e];
  const int tid  = threadIdx.x;
  const int wid  = tid >> 6;
  const int lane = tid & 63;
  const int wr   = wid >> 2;
  const int wc   = wid & 3;
  const int l15  = lane & 15;
  const int l16  = lane >> 4;
  const int NP   = HDIM / 64;

  const unsigned short* gB[4];
  #pragma unroll
  for (int j = 0; j < 4; ++j) {
    int nb = j * 64 + wid * 8 + (lane >> 3);
    int c8 = (lane & 7) ^ (nb & 7);
    int grow = ((nb & 32) ? IDIM : 0) + c0 + ((nb >> 6) << 5) + (nb & 31);
    gB[j] = w13b + ((size_t)e * (2 * IDIM) + grow) * HDIM + c8 * 8;
  }

  for (int rb = rb0; rb * 256 < Ne; rb += 16) {
    const int row0 = rb * 256;
    __syncthreads();

    const unsigned short* gA[4];
    #pragma unroll
    for (int j = 0; j < 4; ++j) {
      int r = j * 64 + wid * 8 + (lane >> 3);
      int c8 = (lane & 7) ^ (r & 7);
      int rr = row0 + r; if (rr > Ne - 1) rr = Ne - 1;
      gA[j] = xb + (size_t)(porig[base + rr] >> 1) * HDIM + c8 * 8;
    }

    f32x4 acc[2][2][4][2];
    #pragma unroll
    for (int qm = 0; qm < 2; ++qm)
      #pragma unroll
      for (int qn = 0; qn < 2; ++qn)
        #pragma unroll
        for (int mi = 0; mi < 4; ++mi)
          #pragma unroll
          for (int ni = 0; ni < 2; ++ni) acc[qm][qn][mi][ni] = (f32x4)(0.0f);

    auto STAGE = [&](int kt) {
      char* d = lds + (kt & 1) * 65536 + wid * 1024;
      #pragma unroll
      for (int j = 0; j < 4; ++j) GLOAD_LDS16(gA[j] + kt * 64, d + j * 8192);
      #pragma unroll
      for (int j = 0; j < 4; ++j) GLOAD_LDS16(gB[j] + kt * 64, d + 32768 + j * 8192);
    };
    auto RD_A = [&](bf16x8 (&dst)[2][4], const char* lb, int qm) {
      #pragma unroll
      for (int ks = 0; ks < 2; ++ks)
        #pragma unroll
        for (int mi = 0; mi < 4; ++mi) {
          int r = wr * 128 + qm * 64 + mi * 16 + l15;
          int j = ks * 4 + l16;
          dst[ks][mi] = *(const bf16x8*)(lb + r * 128 + ((j ^ (r & 7)) << 4));
        }
    };
    auto RD_B = [&](bf16x8 (&dst)[2][2], const char* lb, int qn) {
      #pragma unroll
      for (int ks = 0; ks < 2; ++ks)
        #pragma unroll
        for (int ni = 0; ni < 2; ++ni) {
          int nb = wc * 64 + qn * 32 + ni * 16 + l15;
          int j = ks * 4 + l16;
          dst[ks][ni] = *(const bf16x8*)(lb + 32768 + nb * 128 + ((j ^ (nb & 7)) << 4));
        }
    };
    auto MM = [&](f32x4 (&ac)[4][2], bf16x8 (&a)[2][4], bf16x8 (&b)[2][2]) {
      __builtin_amdgcn_s_setprio(1);
      #pragma unroll
      for (int ks = 0; ks < 2; ++ks)
        #pragma unroll
        for (int mi = 0; mi < 4; ++mi)
          #pragma unroll
          for (int ni = 0; ni < 2; ++ni)
            ac[mi][ni] = __builtin_amdgcn_mfma_f32_16x16x32_bf16(a[ks][mi], b[ks][ni], ac[mi][ni], 0, 0, 0);
      __builtin_amdgcn_s_setprio(0);
    };

    bf16x8 rA0[2][4], rA1[2][4], rB0[2][2], rB1[2][2];

    STAGE(0); STAGE(1);
    VM_WAIT0();  // conservative prologue drain (also covers prior-rb stores)
    __builtin_amdgcn_s_barrier();
    RD_A(rA0, lds, 0); RD_B(rB0, lds, 0);   // 12 outstanding

    for (int i = 0; i < NP; ++i) {
      const char* lb  = lds + (i & 1) * 65536;
      const char* lbn = lds + ((i + 1) & 1) * 65536;
      // ph0
      RD_B(rB1, lb, 1);                    // +4 -> 16
      LGKM_WAIT(4);                        // q0 frags ready
      MM(acc[0][0], rA0, rB0);
      // ph1
      RD_A(rA1, lb, 1);                    // +8 -> 12
      LGKM_WAIT(8);                        // B1 ready
      MM(acc[0][1], rA0, rB1);
      // ph2
      LGKM_WAIT(0);                        // A1 ready
      MM(acc[1][0], rA1, rB0);
      // ph3
      if (i < NP - 1) {
        VM_WAIT0();                        // tile i+1 staged (issued >=1 iter ago)
        __builtin_amdgcn_s_barrier();      // all buf[cur] reads done; buf swap legal
        if (i + 2 < NP) STAGE(i + 2);      // into buf[cur]
        RD_A(rA0, lbn, 0); RD_B(rB0, lbn, 0);  // 12 outstanding for next iter
      }
      MM(acc[1][1], rA1, rB1);
    }

    #pragma unroll
    for (int qm = 0; qm < 2; ++qm)
      #pragma unroll
      for (int mi = 0; mi < 4; ++mi)
        #pragma unroll
        for (int jj = 0; jj < 4; ++jj) {
          int r = wr * 128 + qm * 64 + mi * 16 + l16 * 4 + jj;
          int rr = row0 + r;
          if (rr < Ne) {
            #pragma unroll
            for (int ni = 0; ni < 2; ++ni) {
              float g = acc[qm][0][mi][ni][jj];
              float u = acc[qm][1][mi][ni][jj];
              float a = g / (1.0f + __expf(-g)) * u;
              actb[(size_t)(base + rr) * IDIM + (c0 + wc * 32 + ni * 16 + l15)] = f2bf(a);
            }
          }
        }
  }
}

// ============ GEMM2: yb[pair] = coef * (act @ w2^T), plain bf16 stores ============
__global__ __launch_bounds__(512, 2) void gemm2(const unsigned short* __restrict__ actb,
                                                const unsigned short* __restrict__ w2b,
                                                const int* __restrict__ ctrl,
                                                const int* __restrict__ porig,
                                                const float* __restrict__ pcoef,
                                                unsigned short* __restrict__ yb) {
  __shared__ __align__(16) char lds[133120];
  int*   lpor  = (int*)(lds + 131072);
  float* lcoef = (float*)(lds + 131072 + 1024);
  const int bid = blockIdx.x;
  const int e   = bid & 7;
  const int rb0 = (bid >> 3) & 15;
  const int cb  = bid >> 7;
  const int n0  = cb * 256;
  const int Ne   = ctrl[e];
  const int base = ctrl[8 + e];
  const int tid  = threadIdx.x;
  const int wid  = tid >> 6;
  const int lane = tid & 63;
  const int wr   = wid >> 2;
  const int wc   = wid & 3;
  const int l15  = lane & 15;
  const int l16  = lane >> 4;
  const int NP   = IDIM / 64;

  const unsigned short* gB[4];
  #pragma unroll
  for (int j = 0; j < 4; ++j) {
    int nb = j * 64 + wid * 8 + (lane >> 3);
    int c8 = (lane & 7) ^ (nb & 7);
    gB[j] = w2b + ((size_t)e * HDIM + n0 + nb) * IDIM + c8 * 8;
  }

  for (int rb = rb0; rb * 256 < Ne; rb += 16) {
    const int row0 = rb * 256;
    __syncthreads();

    if (tid < 256) {
      int rr = row0 + tid;
      bool v = rr < Ne;
      lpor[tid]  = v ? porig[base + rr] : 0;
      lcoef[tid] = v ? pcoef[base + rr] : 0.0f;
    }

    const unsigned short* gA[4];
    #pragma unroll
    for (int j = 0; j < 4; ++j) {
      int r = j * 64 + wid * 8 + (lane >> 3);
      int c8 = (lane & 7) ^ (r & 7);
      int rr = row0 + r; if (rr > Ne - 1) rr = Ne - 1;
      gA[j] = actb + (size_t)(base + rr) * IDIM + c8 * 8;
    }

    f32x4 acc[2][2][4][2];
    #pragma unroll
    for (int qm = 0; qm < 2; ++qm)
      #pragma unroll
      for (int qn = 0; qn < 2; ++qn)
        #pragma unroll
        for (int mi = 0; mi < 4; ++mi)
          #pragma unroll
          for (int ni = 0; ni < 2; ++ni) acc[qm][qn][mi][ni] = (f32x4)(0.0f);

    auto STAGE = [&](int kt) {
      char* d = lds + (kt & 1) * 65536 + wid * 1024;
      #pragma unroll
      for (int j = 0; j < 4; ++j) GLOAD_LDS16(gA[j] + kt * 64, d + j * 8192);
      #pragma unroll
      for (int j = 0; j < 4; ++j) GLOAD_LDS16(gB[j] + kt * 64, d + 32768 + j * 8192);
    };
    auto RD_A = [&](bf16x8 (&dst)[2][4], const char* lb, int qm) {
      #pragma unroll
      for (int ks = 0; ks < 2; ++ks)
        #pragma unroll
        for (int mi = 0; mi < 4; ++mi) {
          int r = wr * 128 + qm * 64 + mi * 16 + l15;
          int j = ks * 4 + l16;
          dst[ks][mi] = *(const bf16x8*)(lb + r * 128 + ((j ^ (r & 7)) << 4));
        }
    };
    auto RD_B = [&](bf16x8 (&dst)[2][2], const char* lb, int qn) {
      #pragma unroll
      for (int ks = 0; ks < 2; ++ks)
        #pragma unroll
        for (int ni = 0; ni < 2; ++ni) {
          int nb = wc * 64 + qn * 32 + ni * 16 + l15;
          int j = ks * 4 + l16;
          dst[ks][ni] = *(const bf16x8*)(lb + 32768 + nb * 128 + ((j ^ (nb & 7)) << 4));
        }
    };
    auto MM = [&](f32x4 (&ac)[4][2], bf16x8 (&a)[2][4], bf16x8 (&b)[2][2]) {
      __builtin_amdgcn_s_setprio(1);
      #pragma unroll
      for (int ks = 0; ks < 2; ++ks)
        #pragma unroll
        for (int mi = 0; mi < 4; ++mi)
          #pragma unroll
          for (int ni = 0; ni < 2; ++ni)
            ac[mi][ni] = __builtin_amdgcn_mfma_f32_16x16x32_bf16(a[ks][mi], b[ks][ni], ac[mi][ni], 0, 0, 0);
      __builtin_amdgcn_s_setprio(0);
    };

    bf16x8 rA0[2][4], rA1[2][4], rB0[2][2], rB1[2][2];

    STAGE(0); STAGE(1);
    VM_WAIT0();
    __builtin_amdgcn_s_barrier();
    RD_A(rA0, lds, 0); RD_B(rB0, lds, 0);

    for (int i = 0; i < NP; ++i) {
      const char* lb  = lds + (i & 1) * 65536;
      const char* lbn = lds + ((i + 1) & 1) * 65536;
      RD_B(rB1, lb, 1);
      LGKM_WAIT(4);
      MM(acc[0][0], rA0, rB0);
      RD_A(rA1, lb, 1);
      LGKM_WAIT(8);
      MM(acc[0][1], rA0, rB1);
      LGKM_WAIT(0);
      MM(acc[1][0], rA1, rB0);
      if (i < NP - 1) {
        VM_WAIT0();
        __builtin_amdgcn_s_barrier();
        if (i + 2 < NP) STAGE(i + 2);
        RD_A(rA0, lbn, 0); RD_B(rB0, lbn, 0);
      }
      MM(acc[1][1], rA1, rB1);
    }

    // epilogue: plain bf16 stores to per-pair rows (deterministic; no atomics)
    #pragma unroll
    for (int qm = 0; qm < 2; ++qm)
      #pragma unroll
      for (int mi = 0; mi < 4; ++mi)
        #pragma unroll
        for (int jj = 0; jj < 4; ++jj) {
          int r = wr * 128 + qm * 64 + mi * 16 + l16 * 4 + jj;
          if (row0 + r < Ne) {
            int   p  = lpor[r];
            float cf = lcoef[r];
            #pragma unroll
            for (int qn = 0; qn < 2; ++qn)
              #pragma unroll
              for (int ni = 0; ni < 2; ++ni) {
                int col = n0 + wc * 64 + qn * 32 + ni * 16 + l15;
                yb[(size_t)p * HDIM + col] = f2bf(acc[qm][qn][mi][ni][jj] * cf);
              }
          }
        }
  }
}

// ---------------- reduce: out[t] = yb[2t] + yb[2t+1] ----------------
__global__ __launch_bounds__(256) void reduce2(const unsigned short* __restrict__ yb,
                                               float* __restrict__ out) {
  int i = blockIdx.x * 256 + threadIdx.x;          // one per 8 cols
  int t = i >> 8;                                   // HDIM/8 = 256
  int g = i & 255;
  u16x8 a = *((const u16x8*)(yb + (size_t)(2 * t) * HDIM) + g);
  u16x8 b = *((const u16x8*)(yb + (size_t)(2 * t + 1) * HDIM) + g);
  float4 o0, o1;
  o0.x = bf2f(a[0]) + bf2f(b[0]); o0.y = bf2f(a[1]) + bf2f(b[1]);
  o0.z = bf2f(a[2]) + bf2f(b[2]); o0.w = bf2f(a[3]) + bf2f(b[3]);
  o1.x = bf2f(a[4]) + bf2f(b[4]); o1.y = bf2f(a[5]) + bf2f(b[5]);
  o1.z = bf2f(a[6]) + bf2f(b[6]); o1.w = bf2f(a[7]) + bf2f(b[7]);
  float4* dst = (float4*)(out + (size_t)t * HDIM) + g * 2;
  dst[0] = o0; dst[1] = o1;
}

// ---------------- launcher ----------------
extern "C" void kernel_launch(void* const* d_in, const int* in_sizes, int n_in,
                              void* d_out, int out_size, void* d_ws, size_t ws_size,
                              hipStream_t stream) {
  const float* x   = (const float*)d_in[0];
  const int*   ert = (const int*)d_in[1];
  const float* rw  = (const float*)d_in[2];
  const float* w13 = (const float*)d_in[3];
  const float* w2  = (const float*)d_in[4];
  float* out = (float*)d_out;

  char* ws = (char*)d_ws;
  size_t off = 0;
  auto alloc = [&](size_t bytes) { char* p = ws + off; off += (bytes + 255) & ~255ULL; return p; };
  int*            ctrl  = (int*)           alloc(256);
  int*            porig = (int*)           alloc((size_t)NPAIR * 4);
  float*          pcoef = (float*)         alloc((size_t)NPAIR * 4);
  unsigned short* w2b   = (unsigned short*)alloc((size_t)NEXP * HDIM * IDIM * 2);
  unsigned short* actb  = (unsigned short*)alloc((size_t)NPAIR * IDIM * 2);
  unsigned short* w13b  = (unsigned short*)alloc((size_t)NEXP * 2 * IDIM * HDIM * 2);
  unsigned short* xb    = (unsigned short*)alloc((size_t)TOKS * HDIM * 2);
  // yb (NPAIR x HDIM bf16 = 128 MiB) overlays w13b+xb, both dead after gemm1
  unsigned short* yb    = w13b;

  hipMemsetAsync(ctrl, 0, 256, stream);

  cvt_bf16<<<(NEXP * 2 * IDIM * HDIM / 8) / 256, 256, 0, stream>>>(w13, w13b, NEXP * 2 * IDIM * HDIM / 8);
  cvt_bf16<<<(NEXP * HDIM * IDIM / 8) / 256, 256, 0, stream>>>(w2, w2b, NEXP * HDIM * IDIM / 8);
  cvt_bf16<<<(TOKS * HDIM / 8) / 256, 256, 0, stream>>>(x, xb, TOKS * HDIM / 8);

  route_count  <<<NPAIR / 256, 256, 0, stream>>>(ert, ctrl);
  route_scan   <<<1, 64, 0, stream>>>(ctrl);
  route_scatter<<<NPAIR / 256, 256, 0, stream>>>(ert, rw, ctrl, porig, pcoef);

  gemm1<<<1024, 512, 0, stream>>>(xb, w13b, ctrl, porig, actb);
  gemm2<<<1024, 512, 0, stream>>>(actb, w2b, ctrl, porig, pcoef, yb);
  reduce2<<<(TOKS * HDIM / 8) / 256, 256, 0, stream>>>(yb, out);
}

// Round 6
// 841.760 us; speedup vs baseline: 1.3806x; 1.2887x over previous
//
#include <hip/hip_runtime.h>
#include <hip/hip_bf16.h>
#include <stdint.h>

#define TOKS 16384
#define HDIM 2048
#define IDIM 1024
#define NEXP 8
#define TOPK 2
#define NPAIR (TOKS*TOPK)   // 32768

typedef __attribute__((ext_vector_type(4))) float f32x4;
typedef __attribute__((ext_vector_type(8))) __bf16 bf16x8;
typedef __attribute__((ext_vector_type(8))) unsigned short u16x8;

#define GLOAD_LDS16(gp, lp) \
  __builtin_amdgcn_global_load_lds((const __attribute__((address_space(1))) void*)(gp), \
                                   (__attribute__((address_space(3))) void*)(lp), 16, 0, 0)

#define LGKM_WAITN(n) asm volatile("s_waitcnt lgkmcnt(" #n ")" ::: "memory")
#define VM_WAITN(n)   asm volatile("s_waitcnt vmcnt(" #n ")" ::: "memory")

__device__ __forceinline__ unsigned short f2bf(float f) {
  unsigned int u = __float_as_uint(f);
  u += 0x7FFF + ((u >> 16) & 1);   // RNE
  return (unsigned short)(u >> 16);
}
__device__ __forceinline__ float bf2f(unsigned short h) {
  return __uint_as_float(((unsigned int)h) << 16);
}

// ---------------- conversion: f32 -> bf16, 8 elems/thread ----------------
__global__ __launch_bounds__(256) void cvt_bf16(const float* __restrict__ src,
                                                unsigned short* __restrict__ dst,
                                                int n8) {
  int i = blockIdx.x * 256 + threadIdx.x;
  if (i >= n8) return;
  const float4* s = (const float4*)src + (size_t)i * 2;
  float4 a = s[0], b = s[1];
  u16x8 o;
  o[0] = f2bf(a.x); o[1] = f2bf(a.y); o[2] = f2bf(a.z); o[3] = f2bf(a.w);
  o[4] = f2bf(b.x); o[5] = f2bf(b.y); o[6] = f2bf(b.z); o[7] = f2bf(b.w);
  *((u16x8*)dst + i) = o;
}

// ---------------- routing ----------------
// ctrl ints: [0..7]=counts [8..15]=offsets [16..23]=cursors [24..31]=rowtile prefix [32]=total tiles
__global__ void route_count(const int* __restrict__ ert, int* __restrict__ ctrl) {
  int p = blockIdx.x * 256 + threadIdx.x;
  if (p < NPAIR) atomicAdd(&ctrl[ert[p]], 1);
}

__global__ void route_scan(int* __restrict__ ctrl) {
  if (blockIdx.x == 0 && threadIdx.x == 0) {
    int off = 0;
    for (int e = 0; e < NEXP; ++e) { ctrl[8 + e] = off; ctrl[16 + e] = off; off += ctrl[e]; }
    int toff = 0;
    for (int e = 0; e < NEXP; ++e) { ctrl[24 + e] = toff; toff += (ctrl[e] + 255) >> 8; }
    ctrl[32] = toff;
  }
}

__global__ void route_scatter(const int* __restrict__ ert, const float* __restrict__ rw,
                              int* __restrict__ ctrl, int* __restrict__ porig,
                              float* __restrict__ pcoef, int* __restrict__ pinv) {
  int p = blockIdx.x * 256 + threadIdx.x;
  if (p < NPAIR) {
    int e = ert[p];
    int pos = atomicAdd(&ctrl[16 + e], 1);
    porig[pos] = p;
    pcoef[pos] = rw[p];
    pinv[p]    = pos;
  }
}

// Shared GEMM machinery: 256x256 tile, BK=32, 4-deep LDS ring, counted vmcnt,
// register double-set read-ahead, 1 barrier/iter.
// LDS buf k: A 256x32 bf16 @ k*32768, B 256x32 @ k*32768+16384. Row = 64B = 4x16B
// slots, slot XOR (row>>1)&3 (source pre-swizzled with same involution).

#define RD_SET(lb, A0v, A1v, B0v, B1v) do {                                          \
  _Pragma("unroll") for (int mi = 0; mi < 4; ++mi) {                                 \
    int r_ = wr * 128 + mi * 16 + l15;                                               \
    A0v[mi] = *(const bf16x8*)((lb) + r_ * 64 + ((l16 ^ ((r_ >> 1) & 3)) << 4)); }   \
  _Pragma("unroll") for (int ni = 0; ni < 2; ++ni) {                                 \
    int nb_ = wc * 64 + ni * 16 + l15;                                               \
    B0v[ni] = *(const bf16x8*)((lb) + 16384 + nb_ * 64 + ((l16 ^ ((nb_ >> 1) & 3)) << 4)); } \
  _Pragma("unroll") for (int ni = 0; ni < 2; ++ni) {                                 \
    int nb_ = wc * 64 + 32 + ni * 16 + l15;                                          \
    B1v[ni] = *(const bf16x8*)((lb) + 16384 + nb_ * 64 + ((l16 ^ ((nb_ >> 1) & 3)) << 4)); } \
  _Pragma("unroll") for (int mi = 0; mi < 4; ++mi) {                                 \
    int r_ = wr * 128 + 64 + mi * 16 + l15;                                          \
    A1v[mi] = *(const bf16x8*)((lb) + r_ * 64 + ((l16 ^ ((r_ >> 1) & 3)) << 4)); }   \
} while (0)

#define MMQ(qm, qn, Av, Bv) do {                                                     \
  _Pragma("unroll") for (int mi = 0; mi < 4; ++mi)                                   \
    _Pragma("unroll") for (int ni = 0; ni < 2; ++ni)                                 \
      acc[qm][qn][mi][ni] = __builtin_amdgcn_mfma_f32_16x16x32_bf16(                 \
          Av[mi], Bv[ni], acc[qm][qn][mi][ni], 0, 0, 0);                             \
} while (0)

#define ITER(i, cA0, cA1, cB0, cB1, nA0, nA1, nB0, nB1) do {                         \
  if ((i) + 3 < NT) STAGE((i) + 3);                                                  \
  LGKM_WAITN(6);                                                                     \
  __builtin_amdgcn_s_setprio(1); MMQ(0, 0, cA0, cB0);                                \
  LGKM_WAITN(4);                 MMQ(0, 1, cA0, cB1);                                \
  __builtin_amdgcn_s_setprio(0);                                                     \
  LGKM_WAITN(0);                                                                     \
  if ((i) < NT - 1) {                                                                \
    if ((i) + 3 < NT)       { VM_WAITN(8); }                                         \
    else if ((i) + 3 == NT) { VM_WAITN(4); }                                         \
    else                    { VM_WAITN(0); }                                         \
    __builtin_amdgcn_s_barrier();                                                    \
    RD_SET(lds + (((i) + 1) & 3) * 32768, nA0, nA1, nB0, nB1);                       \
    __builtin_amdgcn_sched_barrier(0);                                               \
  }                                                                                  \
  __builtin_amdgcn_s_setprio(1); MMQ(1, 0, cA1, cB0); MMQ(1, 1, cA1, cB1);           \
  __builtin_amdgcn_s_setprio(0);                                                     \
} while (0)

// ============ GEMM1: act = silu(x@Wg^T)*(x@Wu^T) ============
__global__ __launch_bounds__(512, 2) void gemm1(const unsigned short* __restrict__ xb,
                                                const unsigned short* __restrict__ w13b,
                                                const int* __restrict__ ctrl,
                                                const int* __restrict__ porig,
                                                unsigned short* __restrict__ actb) {
  __shared__ __align__(16) char lds[131072];
  const int bid  = blockIdx.x;
  const int tile = bid >> 3;
  const int cb   = bid & 7;
  if (tile >= ctrl[32]) return;
  int e = 7;
  #pragma unroll
  for (int k = 7; k >= 1; --k) if (tile < ctrl[24 + k]) e = k - 1;
  const int rb   = tile - ctrl[24 + e];
  const int Ne   = ctrl[e];
  const int base = ctrl[8 + e];
  const int row0 = rb * 256;
  const int c0   = cb * 128;
  const int tid  = threadIdx.x;
  const int wid  = tid >> 6;
  const int lane = tid & 63;
  const int wr   = wid >> 2;
  const int wc   = wid & 3;
  const int l15  = lane & 15;
  const int l16  = lane >> 4;
  const int NT   = HDIM / 32;   // 64

  // staging pointers (source pre-swizzled): per gload g, row = g*128+wid*16+(lane>>2)
  const unsigned short *gA0, *gA1, *gB0, *gB1;
  {
    int rl = wid * 16 + (lane >> 2);
    int r0 = rl, r1 = 128 + rl;
    int c80 = (lane & 3) ^ ((r0 >> 1) & 3);
    int c81 = (lane & 3) ^ ((r1 >> 1) & 3);
    int rr0 = row0 + r0; if (rr0 > Ne - 1) rr0 = Ne - 1;
    int rr1 = row0 + r1; if (rr1 > Ne - 1) rr1 = Ne - 1;
    gA0 = xb + (size_t)(porig[base + rr0] >> 1) * HDIM + c80 * 8;
    gA1 = xb + (size_t)(porig[base + rr1] >> 1) * HDIM + c81 * 8;
    // B rows: gate/up interleave: nb&32 -> up half; act col = c0 + (nb>>6)*32 + (nb&31)
    int g0 = ((r0 & 32) ? IDIM : 0) + c0 + ((r0 >> 6) << 5) + (r0 & 31);
    int g1 = ((r1 & 32) ? IDIM : 0) + c0 + ((r1 >> 6) << 5) + (r1 & 31);
    gB0 = w13b + ((size_t)e * (2 * IDIM) + g0) * HDIM + c80 * 8;
    gB1 = w13b + ((size_t)e * (2 * IDIM) + g1) * HDIM + c81 * 8;
  }

  f32x4 acc[2][2][4][2];
  #pragma unroll
  for (int qm = 0; qm < 2; ++qm)
    #pragma unroll
    for (int qn = 0; qn < 2; ++qn)
      #pragma unroll
      for (int mi = 0; mi < 4; ++mi)
        #pragma unroll
        for (int ni = 0; ni < 2; ++ni) acc[qm][qn][mi][ni] = (f32x4)(0.0f);

  auto STAGE = [&](int kt) {
    char* d = lds + (kt & 3) * 32768 + wid * 1024;
    GLOAD_LDS16(gA0 + kt * 32, d);
    GLOAD_LDS16(gA1 + kt * 32, d + 8192);
    GLOAD_LDS16(gB0 + kt * 32, d + 16384);
    GLOAD_LDS16(gB1 + kt * 32, d + 24576);
  };

  bf16x8 A0a[4], A1a[4], B0a[2], B1a[2];
  bf16x8 A0b[4], A1b[4], B0b[2], B1b[2];

  STAGE(0); STAGE(1); STAGE(2);
  VM_WAITN(8);
  __builtin_amdgcn_s_barrier();
  RD_SET(lds, A0a, A1a, B0a, B1a);
  __builtin_amdgcn_sched_barrier(0);

  for (int i = 0; i < NT; i += 2) {
    ITER(i,     A0a, A1a, B0a, B1a, A0b, A1b, B0b, B1b);
    ITER(i + 1, A0b, A1b, B0b, B1b, A0a, A1a, B0a, B1a);
  }

  // epilogue: silu(gate)*up -> bf16 act (qn=0 gate, qn=1 up)
  #pragma unroll
  for (int qm = 0; qm < 2; ++qm)
    #pragma unroll
    for (int mi = 0; mi < 4; ++mi)
      #pragma unroll
      for (int jj = 0; jj < 4; ++jj) {
        int r = wr * 128 + qm * 64 + mi * 16 + l16 * 4 + jj;
        int rr = row0 + r;
        if (rr < Ne) {
          #pragma unroll
          for (int ni = 0; ni < 2; ++ni) {
            float g = acc[qm][0][mi][ni][jj];
            float u = acc[qm][1][mi][ni][jj];
            float a = g / (1.0f + __expf(-g)) * u;
            actb[(size_t)(base + rr) * IDIM + (c0 + wc * 32 + ni * 16 + l15)] = f2bf(a);
          }
        }
      }
}

// ============ GEMM2: yb[pos] = coef * (act @ w2^T), contiguous stores ============
__global__ __launch_bounds__(512, 2) void gemm2(const unsigned short* __restrict__ actb,
                                                const unsigned short* __restrict__ w2b,
                                                const int* __restrict__ ctrl,
                                                const float* __restrict__ pcoef,
                                                unsigned short* __restrict__ yb) {
  __shared__ __align__(16) char lds[131072];
  const int bid  = blockIdx.x;
  const int tile = bid >> 3;
  const int cb   = bid & 7;
  if (tile >= ctrl[32]) return;
  int e = 7;
  #pragma unroll
  for (int k = 7; k >= 1; --k) if (tile < ctrl[24 + k]) e = k - 1;
  const int rb   = tile - ctrl[24 + e];
  const int Ne   = ctrl[e];
  const int base = ctrl[8 + e];
  const int row0 = rb * 256;
  const int n0   = cb * 256;
  const int tid  = threadIdx.x;
  const int wid  = tid >> 6;
  const int lane = tid & 63;
  const int wr   = wid >> 2;
  const int wc   = wid & 3;
  const int l15  = lane & 15;
  const int l16  = lane >> 4;
  const int NT   = IDIM / 32;   // 32

  const unsigned short *gA0, *gA1, *gB0, *gB1;
  {
    int rl = wid * 16 + (lane >> 2);
    int r0 = rl, r1 = 128 + rl;
    int c80 = (lane & 3) ^ ((r0 >> 1) & 3);
    int c81 = (lane & 3) ^ ((r1 >> 1) & 3);
    int rr0 = row0 + r0; if (rr0 > Ne - 1) rr0 = Ne - 1;
    int rr1 = row0 + r1; if (rr1 > Ne - 1) rr1 = Ne - 1;
    gA0 = actb + (size_t)(base + rr0) * IDIM + c80 * 8;
    gA1 = actb + (size_t)(base + rr1) * IDIM + c81 * 8;
    gB0 = w2b + ((size_t)e * HDIM + n0 + r0) * IDIM + c80 * 8;
    gB1 = w2b + ((size_t)e * HDIM + n0 + r1) * IDIM + c81 * 8;
  }

  f32x4 acc[2][2][4][2];
  #pragma unroll
  for (int qm = 0; qm < 2; ++qm)
    #pragma unroll
    for (int qn = 0; qn < 2; ++qn)
      #pragma unroll
      for (int mi = 0; mi < 4; ++mi)
        #pragma unroll
        for (int ni = 0; ni < 2; ++ni) acc[qm][qn][mi][ni] = (f32x4)(0.0f);

  auto STAGE = [&](int kt) {
    char* d = lds + (kt & 3) * 32768 + wid * 1024;
    GLOAD_LDS16(gA0 + kt * 32, d);
    GLOAD_LDS16(gA1 + kt * 32, d + 8192);
    GLOAD_LDS16(gB0 + kt * 32, d + 16384);
    GLOAD_LDS16(gB1 + kt * 32, d + 24576);
  };

  bf16x8 A0a[4], A1a[4], B0a[2], B1a[2];
  bf16x8 A0b[4], A1b[4], B0b[2], B1b[2];

  STAGE(0); STAGE(1); STAGE(2);
  VM_WAITN(8);
  __builtin_amdgcn_s_barrier();
  RD_SET(lds, A0a, A1a, B0a, B1a);
  __builtin_amdgcn_sched_barrier(0);

  for (int i = 0; i < NT; i += 2) {
    ITER(i,     A0a, A1a, B0a, B1a, A0b, A1b, B0b, B1b);
    ITER(i + 1, A0b, A1b, B0b, B1b, A0a, A1a, B0a, B1a);
  }

  // epilogue: contiguous bf16 stores at sorted position, scaled by router coef
  #pragma unroll
  for (int qm = 0; qm < 2; ++qm)
    #pragma unroll
    for (int mi = 0; mi < 4; ++mi)
      #pragma unroll
      for (int jj = 0; jj < 4; ++jj) {
        int r = wr * 128 + qm * 64 + mi * 16 + l16 * 4 + jj;
        int rr = row0 + r;
        if (rr < Ne) {
          float cf = pcoef[base + rr];
          #pragma unroll
          for (int qn = 0; qn < 2; ++qn)
            #pragma unroll
            for (int ni = 0; ni < 2; ++ni) {
              int col = n0 + wc * 64 + qn * 32 + ni * 16 + l15;
              yb[(size_t)(base + rr) * HDIM + col] = f2bf(acc[qm][qn][mi][ni][jj] * cf);
            }
        }
      }
}

// ---------------- reduce: out[t] = yb[pinv[2t]] + yb[pinv[2t+1]] ----------------
__global__ __launch_bounds__(256) void reduce2(const unsigned short* __restrict__ yb,
                                               const int* __restrict__ pinv,
                                               float* __restrict__ out) {
  int i = blockIdx.x * 256 + threadIdx.x;
  int t = i >> 8;                                   // 256 thread-groups of 8 cols
  int g = i & 255;
  int p0 = pinv[2 * t], p1 = pinv[2 * t + 1];
  u16x8 a = *((const u16x8*)(yb + (size_t)p0 * HDIM) + g);
  u16x8 b = *((const u16x8*)(yb + (size_t)p1 * HDIM) + g);
  float4 o0, o1;
  o0.x = bf2f(a[0]) + bf2f(b[0]); o0.y = bf2f(a[1]) + bf2f(b[1]);
  o0.z = bf2f(a[2]) + bf2f(b[2]); o0.w = bf2f(a[3]) + bf2f(b[3]);
  o1.x = bf2f(a[4]) + bf2f(b[4]); o1.y = bf2f(a[5]) + bf2f(b[5]);
  o1.z = bf2f(a[6]) + bf2f(b[6]); o1.w = bf2f(a[7]) + bf2f(b[7]);
  float4* dst = (float4*)(out + (size_t)t * HDIM) + g * 2;
  dst[0] = o0; dst[1] = o1;
}

// ---------------- launcher ----------------
extern "C" void kernel_launch(void* const* d_in, const int* in_sizes, int n_in,
                              void* d_out, int out_size, void* d_ws, size_t ws_size,
                              hipStream_t stream) {
  const float* x   = (const float*)d_in[0];
  const int*   ert = (const int*)d_in[1];
  const float* rw  = (const float*)d_in[2];
  const float* w13 = (const float*)d_in[3];
  const float* w2  = (const float*)d_in[4];
  float* out = (float*)d_out;

  char* ws = (char*)d_ws;
  size_t off = 0;
  auto alloc = [&](size_t bytes) { char* p = ws + off; off += (bytes + 255) & ~255ULL; return p; };
  int*            ctrl  = (int*)           alloc(256);
  int*            porig = (int*)           alloc((size_t)NPAIR * 4);
  float*          pcoef = (float*)         alloc((size_t)NPAIR * 4);
  int*            pinv  = (int*)           alloc((size_t)NPAIR * 4);
  unsigned short* w2b   = (unsigned short*)alloc((size_t)NEXP * HDIM * IDIM * 2);
  unsigned short* actb  = (unsigned short*)alloc((size_t)NPAIR * IDIM * 2);
  unsigned short* w13b  = (unsigned short*)alloc((size_t)NEXP * 2 * IDIM * HDIM * 2);
  unsigned short* xb    = (unsigned short*)alloc((size_t)TOKS * HDIM * 2);
  // yb (NPAIR x HDIM bf16 = 128 MiB) overlays w13b (dead after gemm1)
  unsigned short* yb    = w13b;

  hipMemsetAsync(ctrl, 0, 256, stream);

  cvt_bf16<<<(NEXP * 2 * IDIM * HDIM / 8) / 256, 256, 0, stream>>>(w13, w13b, NEXP * 2 * IDIM * HDIM / 8);
  cvt_bf16<<<(NEXP * HDIM * IDIM / 8) / 256, 256, 0, stream>>>(w2, w2b, NEXP * HDIM * IDIM / 8);
  cvt_bf16<<<(TOKS * HDIM / 8) / 256, 256, 0, stream>>>(x, xb, TOKS * HDIM / 8);

  route_count  <<<NPAIR / 256, 256, 0, stream>>>(ert, ctrl);
  route_scan   <<<1, 64, 0, stream>>>(ctrl);
  route_scatter<<<NPAIR / 256, 256, 0, stream>>>(ert, rw, ctrl, porig, pcoef, pinv);

  gemm1<<<136 * 8, 512, 0, stream>>>(xb, w13b, ctrl, porig, actb);
  gemm2<<<136 * 8, 512, 0, stream>>>(actb, w2b, ctrl, pcoef, yb);
  reduce2<<<(TOKS * HDIM / 8) / 256, 256, 0, stream>>>(yb, pinv, out);
}

// Round 7
// 821.781 us; speedup vs baseline: 1.4142x; 1.0243x over previous
//
#include <hip/hip_runtime.h>
#include <hip/hip_bf16.h>
#include <stdint.h>

#define TOKS 16384
#define HDIM 2048
#define IDIM 1024
#define NEXP 8
#define TOPK 2
#define NPAIR (TOKS*TOPK)   // 32768

typedef __attribute__((ext_vector_type(4))) float f32x4;
typedef __attribute__((ext_vector_type(8))) __bf16 bf16x8;
typedef __attribute__((ext_vector_type(8))) unsigned short u16x8;

#define GLOAD_LDS16(gp, lp) \
  __builtin_amdgcn_global_load_lds((const __attribute__((address_space(1))) void*)(gp), \
                                   (__attribute__((address_space(3))) void*)(lp), 16, 0, 0)

#define LGKM_WAITN(n) asm volatile("s_waitcnt lgkmcnt(" #n ")" ::: "memory")
#define VM_WAITN(n)   asm volatile("s_waitcnt vmcnt(" #n ")" ::: "memory")

__device__ __forceinline__ unsigned short f2bf(float f) {
  unsigned int u = __float_as_uint(f);
  u += 0x7FFF + ((u >> 16) & 1);   // RNE
  return (unsigned short)(u >> 16);
}
__device__ __forceinline__ float bf2f(unsigned short h) {
  return __uint_as_float(((unsigned int)h) << 16);
}

// ---------------- fused conversion: f32 -> bf16 for w13, w2, x ----------------
#define W13_N8 (NEXP * 2 * IDIM * HDIM / 8)   // 4194304
#define W2_N8  (NEXP * HDIM * IDIM / 8)       // 2097152
#define X_N8   (TOKS * HDIM / 8)              // 4194304
__global__ __launch_bounds__(256) void cvt_all(const float* __restrict__ w13,
                                               const float* __restrict__ w2,
                                               const float* __restrict__ x,
                                               unsigned short* __restrict__ w13b,
                                               unsigned short* __restrict__ w2b,
                                               unsigned short* __restrict__ xb) {
  int i = blockIdx.x * 256 + threadIdx.x;
  const float* s; unsigned short* d; int j;
  if (i < W13_N8)              { s = w13; d = w13b; j = i; }
  else if (i < W13_N8 + W2_N8) { s = w2;  d = w2b;  j = i - W13_N8; }
  else                         { s = x;   d = xb;   j = i - W13_N8 - W2_N8; }
  const float4* sp = (const float4*)s + (size_t)j * 2;
  float4 a = sp[0], b = sp[1];
  u16x8 o;
  o[0] = f2bf(a.x); o[1] = f2bf(a.y); o[2] = f2bf(a.z); o[3] = f2bf(a.w);
  o[4] = f2bf(b.x); o[5] = f2bf(b.y); o[6] = f2bf(b.z); o[7] = f2bf(b.w);
  *((u16x8*)d + j) = o;
}

// ---------------- routing ----------------
// ctrl ints: [0..7]=counts [8..15]=offsets [16..23]=cursors [24..31]=rowtile prefix [32]=total tiles
__global__ void route_count(const int* __restrict__ ert, int* __restrict__ ctrl) {
  int p = blockIdx.x * 256 + threadIdx.x;
  if (p < NPAIR) atomicAdd(&ctrl[ert[p]], 1);
}

__global__ void route_scan(int* __restrict__ ctrl) {
  if (blockIdx.x == 0 && threadIdx.x == 0) {
    int off = 0;
    for (int e = 0; e < NEXP; ++e) { ctrl[8 + e] = off; ctrl[16 + e] = off; off += ctrl[e]; }
    int toff = 0;
    for (int e = 0; e < NEXP; ++e) { ctrl[24 + e] = toff; toff += (ctrl[e] + 255) >> 8; }
    ctrl[32] = toff;
  }
}

__global__ void route_scatter(const int* __restrict__ ert, const float* __restrict__ rw,
                              int* __restrict__ ctrl, int* __restrict__ porig,
                              float* __restrict__ pcoef, int* __restrict__ pinv) {
  int p = blockIdx.x * 256 + threadIdx.x;
  if (p < NPAIR) {
    int e = ert[p];
    int pos = atomicAdd(&ctrl[16 + e], 1);
    porig[pos] = p;
    pcoef[pos] = rw[p];
    pinv[p]    = pos;
  }
}

// Shared GEMM machinery: 256x256 tile, BK=32, 4-deep LDS ring, counted vmcnt,
// register double-set read-ahead, 1 barrier/iter.
// LDS buf k: A 256x32 bf16 @ k*32768, B 256x32 @ k*32768+16384. Row = 64B = 4x16B
// slots, slot XOR (row>>1)&3 (source pre-swizzled with same involution).

#define RD_SET(lb, A0v, A1v, B0v, B1v) do {                                          \
  _Pragma("unroll") for (int mi = 0; mi < 4; ++mi) {                                 \
    int r_ = wr * 128 + mi * 16 + l15;                                               \
    A0v[mi] = *(const bf16x8*)((lb) + r_ * 64 + ((l16 ^ ((r_ >> 1) & 3)) << 4)); }   \
  _Pragma("unroll") for (int ni = 0; ni < 2; ++ni) {                                 \
    int nb_ = wc * 64 + ni * 16 + l15;                                               \
    B0v[ni] = *(const bf16x8*)((lb) + 16384 + nb_ * 64 + ((l16 ^ ((nb_ >> 1) & 3)) << 4)); } \
  _Pragma("unroll") for (int ni = 0; ni < 2; ++ni) {                                 \
    int nb_ = wc * 64 + 32 + ni * 16 + l15;                                          \
    B1v[ni] = *(const bf16x8*)((lb) + 16384 + nb_ * 64 + ((l16 ^ ((nb_ >> 1) & 3)) << 4)); } \
  _Pragma("unroll") for (int mi = 0; mi < 4; ++mi) {                                 \
    int r_ = wr * 128 + 64 + mi * 16 + l15;                                          \
    A1v[mi] = *(const bf16x8*)((lb) + r_ * 64 + ((l16 ^ ((r_ >> 1) & 3)) << 4)); }   \
} while (0)

#define MMQ(qm, qn, Av, Bv) do {                                                     \
  _Pragma("unroll") for (int mi = 0; mi < 4; ++mi)                                   \
    _Pragma("unroll") for (int ni = 0; ni < 2; ++ni)                                 \
      acc[qm][qn][mi][ni] = __builtin_amdgcn_mfma_f32_16x16x32_bf16(                 \
          Av[mi], Bv[ni], acc[qm][qn][mi][ni], 0, 0, 0);                             \
} while (0)

#define ITER(i, cA0, cA1, cB0, cB1, nA0, nA1, nB0, nB1) do {                         \
  if ((i) + 3 < NT) STAGE((i) + 3);                                                  \
  LGKM_WAITN(6);                                                                     \
  __builtin_amdgcn_s_setprio(1); MMQ(0, 0, cA0, cB0);                                \
  LGKM_WAITN(4);                 MMQ(0, 1, cA0, cB1);                                \
  __builtin_amdgcn_s_setprio(0);                                                     \
  LGKM_WAITN(0);                                                                     \
  if ((i) < NT - 1) {                                                                \
    if ((i) + 3 < NT)       { VM_WAITN(8); }                                         \
    else if ((i) + 3 == NT) { VM_WAITN(4); }                                         \
    else                    { VM_WAITN(0); }                                         \
    __builtin_amdgcn_s_barrier();                                                    \
    RD_SET(lds + (((i) + 1) & 3) * 32768, nA0, nA1, nB0, nB1);                       \
    __builtin_amdgcn_sched_barrier(0);                                               \
  }                                                                                  \
  __builtin_amdgcn_s_setprio(1); MMQ(1, 0, cA1, cB0); MMQ(1, 1, cA1, cB1);           \
  __builtin_amdgcn_s_setprio(0);                                                     \
} while (0)

// XCD-co-located block map: the 8 cb-blocks of one tile occupy 8 consecutive
// dispatch slots of the SAME XCD (bid = x + 8*(tg*8+cb), tile = tg*8+x).
#define TILE_MAP()                                                                   \
  const int x_ = bid & 7, k_ = bid >> 3;                                             \
  const int cb = k_ & 7;                                                             \
  const int tile = ((k_ >> 3) << 3) + x_;

// ============ GEMM1: act = silu(x@Wg^T)*(x@Wu^T) ============
__global__ __launch_bounds__(512, 2) void gemm1(const unsigned short* __restrict__ xb,
                                                const unsigned short* __restrict__ w13b,
                                                const int* __restrict__ ctrl,
                                                const int* __restrict__ porig,
                                                unsigned short* __restrict__ actb) {
  __shared__ __align__(16) char lds[131072];
  const int bid  = blockIdx.x;
  TILE_MAP();
  if (tile >= ctrl[32]) return;
  int e = 7;
  #pragma unroll
  for (int k = 7; k >= 1; --k) if (tile < ctrl[24 + k]) e = k - 1;
  const int rb   = tile - ctrl[24 + e];
  const int Ne   = ctrl[e];
  const int base = ctrl[8 + e];
  const int row0 = rb * 256;
  const int c0   = cb * 128;
  const int tid  = threadIdx.x;
  const int wid  = tid >> 6;
  const int lane = tid & 63;
  const int wr   = wid >> 2;
  const int wc   = wid & 3;
  const int l15  = lane & 15;
  const int l16  = lane >> 4;
  const int NT   = HDIM / 32;   // 64

  // staging pointers (source pre-swizzled): per gload g, row = g*128+wid*16+(lane>>2)
  const unsigned short *gA0, *gA1, *gB0, *gB1;
  {
    int rl = wid * 16 + (lane >> 2);
    int r0 = rl, r1 = 128 + rl;
    int c80 = (lane & 3) ^ ((r0 >> 1) & 3);
    int c81 = (lane & 3) ^ ((r1 >> 1) & 3);
    int rr0 = row0 + r0; if (rr0 > Ne - 1) rr0 = Ne - 1;
    int rr1 = row0 + r1; if (rr1 > Ne - 1) rr1 = Ne - 1;
    gA0 = xb + (size_t)(porig[base + rr0] >> 1) * HDIM + c80 * 8;
    gA1 = xb + (size_t)(porig[base + rr1] >> 1) * HDIM + c81 * 8;
    // B rows: gate/up interleave: nb&32 -> up half; act col = c0 + (nb>>6)*32 + (nb&31)
    int g0 = ((r0 & 32) ? IDIM : 0) + c0 + ((r0 >> 6) << 5) + (r0 & 31);
    int g1 = ((r1 & 32) ? IDIM : 0) + c0 + ((r1 >> 6) << 5) + (r1 & 31);
    gB0 = w13b + ((size_t)e * (2 * IDIM) + g0) * HDIM + c80 * 8;
    gB1 = w13b + ((size_t)e * (2 * IDIM) + g1) * HDIM + c81 * 8;
  }

  f32x4 acc[2][2][4][2];
  #pragma unroll
  for (int qm = 0; qm < 2; ++qm)
    #pragma unroll
    for (int qn = 0; qn < 2; ++qn)
      #pragma unroll
      for (int mi = 0; mi < 4; ++mi)
        #pragma unroll
        for (int ni = 0; ni < 2; ++ni) acc[qm][qn][mi][ni] = (f32x4)(0.0f);

  auto STAGE = [&](int kt) {
    char* d = lds + (kt & 3) * 32768 + wid * 1024;
    GLOAD_LDS16(gA0 + kt * 32, d);
    GLOAD_LDS16(gA1 + kt * 32, d + 8192);
    GLOAD_LDS16(gB0 + kt * 32, d + 16384);
    GLOAD_LDS16(gB1 + kt * 32, d + 24576);
  };

  bf16x8 A0a[4], A1a[4], B0a[2], B1a[2];
  bf16x8 A0b[4], A1b[4], B0b[2], B1b[2];

  STAGE(0); STAGE(1); STAGE(2);
  VM_WAITN(8);
  __builtin_amdgcn_s_barrier();
  RD_SET(lds, A0a, A1a, B0a, B1a);
  __builtin_amdgcn_sched_barrier(0);

  for (int i = 0; i < NT; i += 2) {
    ITER(i,     A0a, A1a, B0a, B1a, A0b, A1b, B0b, B1b);
    ITER(i + 1, A0b, A1b, B0b, B1b, A0a, A1a, B0a, B1a);
  }

  // epilogue: silu(gate)*up -> bf16 act (qn=0 gate, qn=1 up)
  #pragma unroll
  for (int qm = 0; qm < 2; ++qm)
    #pragma unroll
    for (int mi = 0; mi < 4; ++mi)
      #pragma unroll
      for (int jj = 0; jj < 4; ++jj) {
        int r = wr * 128 + qm * 64 + mi * 16 + l16 * 4 + jj;
        int rr = row0 + r;
        if (rr < Ne) {
          #pragma unroll
          for (int ni = 0; ni < 2; ++ni) {
            float g = acc[qm][0][mi][ni][jj];
            float u = acc[qm][1][mi][ni][jj];
            float a = g / (1.0f + __expf(-g)) * u;
            actb[(size_t)(base + rr) * IDIM + (c0 + wc * 32 + ni * 16 + l15)] = f2bf(a);
          }
        }
      }
}

// ============ GEMM2: yb[pos] = coef * (act @ w2^T), contiguous stores ============
__global__ __launch_bounds__(512, 2) void gemm2(const unsigned short* __restrict__ actb,
                                                const unsigned short* __restrict__ w2b,
                                                const int* __restrict__ ctrl,
                                                const float* __restrict__ pcoef,
                                                unsigned short* __restrict__ yb) {
  __shared__ __align__(16) char lds[131072];
  const int bid  = blockIdx.x;
  TILE_MAP();
  if (tile >= ctrl[32]) return;
  int e = 7;
  #pragma unroll
  for (int k = 7; k >= 1; --k) if (tile < ctrl[24 + k]) e = k - 1;
  const int rb   = tile - ctrl[24 + e];
  const int Ne   = ctrl[e];
  const int base = ctrl[8 + e];
  const int row0 = rb * 256;
  const int n0   = cb * 256;
  const int tid  = threadIdx.x;
  const int wid  = tid >> 6;
  const int lane = tid & 63;
  const int wr   = wid >> 2;
  const int wc   = wid & 3;
  const int l15  = lane & 15;
  const int l16  = lane >> 4;
  const int NT   = IDIM / 32;   // 32

  const unsigned short *gA0, *gA1, *gB0, *gB1;
  {
    int rl = wid * 16 + (lane >> 2);
    int r0 = rl, r1 = 128 + rl;
    int c80 = (lane & 3) ^ ((r0 >> 1) & 3);
    int c81 = (lane & 3) ^ ((r1 >> 1) & 3);
    int rr0 = row0 + r0; if (rr0 > Ne - 1) rr0 = Ne - 1;
    int rr1 = row0 + r1; if (rr1 > Ne - 1) rr1 = Ne - 1;
    gA0 = actb + (size_t)(base + rr0) * IDIM + c80 * 8;
    gA1 = actb + (size_t)(base + rr1) * IDIM + c81 * 8;
    gB0 = w2b + ((size_t)e * HDIM + n0 + r0) * IDIM + c80 * 8;
    gB1 = w2b + ((size_t)e * HDIM + n0 + r1) * IDIM + c81 * 8;
  }

  f32x4 acc[2][2][4][2];
  #pragma unroll
  for (int qm = 0; qm < 2; ++qm)
    #pragma unroll
    for (int qn = 0; qn < 2; ++qn)
      #pragma unroll
      for (int mi = 0; mi < 4; ++mi)
        #pragma unroll
        for (int ni = 0; ni < 2; ++ni) acc[qm][qn][mi][ni] = (f32x4)(0.0f);

  auto STAGE = [&](int kt) {
    char* d = lds + (kt & 3) * 32768 + wid * 1024;
    GLOAD_LDS16(gA0 + kt * 32, d);
    GLOAD_LDS16(gA1 + kt * 32, d + 8192);
    GLOAD_LDS16(gB0 + kt * 32, d + 16384);
    GLOAD_LDS16(gB1 + kt * 32, d + 24576);
  };

  bf16x8 A0a[4], A1a[4], B0a[2], B1a[2];
  bf16x8 A0b[4], A1b[4], B0b[2], B1b[2];

  STAGE(0); STAGE(1); STAGE(2);
  VM_WAITN(8);
  __builtin_amdgcn_s_barrier();
  RD_SET(lds, A0a, A1a, B0a, B1a);
  __builtin_amdgcn_sched_barrier(0);

  for (int i = 0; i < NT; i += 2) {
    ITER(i,     A0a, A1a, B0a, B1a, A0b, A1b, B0b, B1b);
    ITER(i + 1, A0b, A1b, B0b, B1b, A0a, A1a, B0a, B1a);
  }

  // epilogue: contiguous bf16 stores at sorted position, scaled by router coef
  #pragma unroll
  for (int qm = 0; qm < 2; ++qm)
    #pragma unroll
    for (int mi = 0; mi < 4; ++mi)
      #pragma unroll
      for (int jj = 0; jj < 4; ++jj) {
        int r = wr * 128 + qm * 64 + mi * 16 + l16 * 4 + jj;
        int rr = row0 + r;
        if (rr < Ne) {
          float cf = pcoef[base + rr];
          #pragma unroll
          for (int qn = 0; qn < 2; ++qn)
            #pragma unroll
            for (int ni = 0; ni < 2; ++ni) {
              int col = n0 + wc * 64 + qn * 32 + ni * 16 + l15;
              yb[(size_t)(base + rr) * HDIM + col] = f2bf(acc[qm][qn][mi][ni][jj] * cf);
            }
        }
      }
}

// ---------------- reduce: out[t] = yb[pinv[2t]] + yb[pinv[2t+1]] ----------------
__global__ __launch_bounds__(256) void reduce2(const unsigned short* __restrict__ yb,
                                               const int* __restrict__ pinv,
                                               float* __restrict__ out) {
  int i = blockIdx.x * 256 + threadIdx.x;
  int t = i >> 8;                                   // 256 thread-groups of 8 cols
  int g = i & 255;
  int p0 = pinv[2 * t], p1 = pinv[2 * t + 1];
  u16x8 a = *((const u16x8*)(yb + (size_t)p0 * HDIM) + g);
  u16x8 b = *((const u16x8*)(yb + (size_t)p1 * HDIM) + g);
  float4 o0, o1;
  o0.x = bf2f(a[0]) + bf2f(b[0]); o0.y = bf2f(a[1]) + bf2f(b[1]);
  o0.z = bf2f(a[2]) + bf2f(b[2]); o0.w = bf2f(a[3]) + bf2f(b[3]);
  o1.x = bf2f(a[4]) + bf2f(b[4]); o1.y = bf2f(a[5]) + bf2f(b[5]);
  o1.z = bf2f(a[6]) + bf2f(b[6]); o1.w = bf2f(a[7]) + bf2f(b[7]);
  float4* dst = (float4*)(out + (size_t)t * HDIM) + g * 2;
  dst[0] = o0; dst[1] = o1;
}

// ---------------- launcher ----------------
extern "C" void kernel_launch(void* const* d_in, const int* in_sizes, int n_in,
                              void* d_out, int out_size, void* d_ws, size_t ws_size,
                              hipStream_t stream) {
  const float* x   = (const float*)d_in[0];
  const int*   ert = (const int*)d_in[1];
  const float* rw  = (const float*)d_in[2];
  const float* w13 = (const float*)d_in[3];
  const float* w2  = (const float*)d_in[4];
  float* out = (float*)d_out;

  char* ws = (char*)d_ws;
  size_t off = 0;
  auto alloc = [&](size_t bytes) { char* p = ws + off; off += (bytes + 255) & ~255ULL; return p; };
  int*            ctrl  = (int*)           alloc(256);
  int*            porig = (int*)           alloc((size_t)NPAIR * 4);
  float*          pcoef = (float*)         alloc((size_t)NPAIR * 4);
  int*            pinv  = (int*)           alloc((size_t)NPAIR * 4);
  unsigned short* w2b   = (unsigned short*)alloc((size_t)NEXP * HDIM * IDIM * 2);
  unsigned short* actb  = (unsigned short*)alloc((size_t)NPAIR * IDIM * 2);
  unsigned short* w13b  = (unsigned short*)alloc((size_t)NEXP * 2 * IDIM * HDIM * 2);
  unsigned short* xb    = (unsigned short*)alloc((size_t)TOKS * HDIM * 2);
  // yb (NPAIR x HDIM bf16 = 128 MiB) overlays w13b (dead after gemm1)
  unsigned short* yb    = w13b;

  hipMemsetAsync(ctrl, 0, 256, stream);

  cvt_all<<<(W13_N8 + W2_N8 + X_N8) / 256, 256, 0, stream>>>(w13, w2, x, w13b, w2b, xb);

  route_count  <<<NPAIR / 256, 256, 0, stream>>>(ert, ctrl);
  route_scan   <<<1, 64, 0, stream>>>(ert ? ctrl : ctrl);
  route_scatter<<<NPAIR / 256, 256, 0, stream>>>(ert, rw, ctrl, porig, pcoef, pinv);

  gemm1<<<136 * 8, 512, 0, stream>>>(xb, w13b, ctrl, porig, actb);
  gemm2<<<136 * 8, 512, 0, stream>>>(actb, w2b, ctrl, pcoef, yb);
  reduce2<<<(TOKS * HDIM / 8) / 256, 256, 0, stream>>>(yb, pinv, out);
}